// Round 3
// baseline (543.096 us; speedup 1.0000x reference)
//
#include <hip/hip_runtime.h>

typedef short short8 __attribute__((ext_vector_type(8)));
typedef float f32x4 __attribute__((ext_vector_type(4)));
typedef float v2f __attribute__((ext_vector_type(2)));
typedef unsigned int uint32;
typedef uint32 u32x4 __attribute__((ext_vector_type(4)));

namespace {
constexpr int S_LEN = 512, BATCH = 1024, TAG = 64;
constexpr int START_IDX = 0, END_IDX = 1;
constexpr int K_CH = 4;              // chunks per batch
constexpr int L_CH = S_LEN / K_CH;   // 128 steps per chunk
constexpr int PD = 4;                // prefetch depth == renorm cadence

// pack two fp32 -> two bf16, round-half-up (kills truncation bias over 512 steps)
__device__ __forceinline__ uint32 pack_bf16_rnd(float lo, float hi) {
  uint32 a = __float_as_uint(lo) + 0x8000u;
  uint32 b = __float_as_uint(hi) + 0x8000u;
  return __builtin_amdgcn_perm(b, a, 0x07060302u);
}
}  // namespace

// ---------------- kernel 1: per-(batch,chunk) transfer matrix via MFMA ----------------
// M <- diag(exp(feat_s)) * (E * M), E = exp(trans) const in A-frags.
//
// LDS layout (swizzled, no pad, 8 KiB): element (k,n) at byte
//   ((k>>5)*4 + (n>>4))*1024 + ((k>>3)&3)*256 + (n&15)*16 + (k&7)*2
// => B-frag read (kb,nt): block (kb*4+nt), byte = lane*16  -- fully lane-contiguous b128
// => D-write (mt,nt): 8B at ((mt>>1)*4+nt)*1024 + ((mt&1)*2+(quad>>1))*256 + c0*16 + (quad&1)*8
//    (2 distinct addrs per bank per half-wave: free per m136)
__global__ __launch_bounds__(64) void crf_chunk_kernel(
    const float* __restrict__ feats, const float* __restrict__ mask,
    const float* __restrict__ trans, uint32* __restrict__ wsM,
    float* __restrict__ wsL) {
  const int bc = blockIdx.x;
  const int b = bc >> 2;
  const int c = bc & 3;
  const int lane = threadIdx.x;
  const int c0 = lane & 15, quad = lane >> 4;

  __shared__ __align__(16) unsigned short Mlds[TAG * TAG];
  __shared__ __align__(16) float f_lds[TAG];

  // ---- init M = I ----
  {
    u32x4 z = {0u, 0u, 0u, 0u};
    u32x4* p = (u32x4*)Mlds;
#pragma unroll
    for (int t = 0; t < 8; ++t) p[lane + 64 * t] = z;
    __builtin_amdgcn_wave_barrier();
    char* idp = (char*)Mlds + ((lane >> 5) * 4 + (lane >> 4)) * 1024 +
                ((lane >> 3) & 3) * 256 + (lane & 15) * 16 + (lane & 7) * 2;
    *(unsigned short*)idp = 0x3F80;  // bf16 1.0 at (k=lane, n=lane)
    __builtin_amdgcn_wave_barrier();
  }

  // ---- E fragments (A-operand): A[m=c0+16mt][k=quad*8+j] per (mt,kb) ----
  short8 Efrag[4][2];
#pragma unroll
  for (int mt = 0; mt < 4; ++mt)
#pragma unroll
    for (int kb = 0; kb < 2; ++kb) {
      const float* src = trans + (mt * 16 + c0) * TAG + kb * 32 + quad * 8;
      f32x4 t0, t1;
      __builtin_memcpy(&t0, src, 16);
      __builtin_memcpy(&t1, src + 4, 16);
      uint32 uu[4];
      uu[0] = pack_bf16_rnd(__expf(t0.x), __expf(t0.y));  // exp(-1e4) -> 0, no NaN
      uu[1] = pack_bf16_rnd(__expf(t0.z), __expf(t0.w));
      uu[2] = pack_bf16_rnd(__expf(t1.x), __expf(t1.y));
      uu[3] = pack_bf16_rnd(__expf(t1.z), __expf(t1.w));
      __builtin_memcpy(&Efrag[mt][kb], uu, 16);
    }

  const size_t FSTRIDE = (size_t)BATCH * TAG;
  const float* fptr = feats + (size_t)(c * L_CH) * FSTRIDE + (size_t)b * TAG + lane;
  const float* mptr = mask + (size_t)(c * L_CH) * BATCH + b;

  float fbuf[PD], mbuf[PD];
#pragma unroll
  for (int d = 0; d < PD; ++d) {
    fbuf[d] = fptr[(size_t)d * FSTRIDE];
    mbuf[d] = mptr[(size_t)d * BATCH];
  }

  float acc_log = 0.0f;

  for (int sb = 0; sb < L_CH; sb += PD) {
#pragma unroll
    for (int d = 0; d < PD; ++d) {
      const float fcur = fbuf[d];
      const float mcur = mbuf[d];
      if (mcur == 0.0f) goto fin;  // mask monotone: rest of chunk is identity
      int sp = sb + d + PD;
      sp = (sp < L_CH) ? sp : (L_CH - 1);
      fbuf[d] = fptr[(size_t)sp * FSTRIDE];
      mbuf[d] = mptr[(size_t)sp * BATCH];

      f_lds[lane] = __expf(fcur);  // row scales (|feat| small, no anchor needed)

      // B-frags: lane-contiguous b128 per (kb,nt)
      short8 Bf[2][4];
#pragma unroll
      for (int kb = 0; kb < 2; ++kb)
#pragma unroll
        for (int nt = 0; nt < 4; ++nt)
          __builtin_memcpy(&Bf[kb][nt], (const char*)Mlds + (kb * 4 + nt) * 1024 + lane * 16, 16);

      // G = E*M : 4x4 tiles, K=64 via 2 chained MFMAs
      f32x4 g[4][4];
#pragma unroll
      for (int mt = 0; mt < 4; ++mt)
#pragma unroll
        for (int nt = 0; nt < 4; ++nt) {
          f32x4 z = {0.f, 0.f, 0.f, 0.f};
          z = __builtin_amdgcn_mfma_f32_16x16x32_bf16(Efrag[mt][0], Bf[0][nt], z, 0, 0, 0);
          g[mt][nt] = __builtin_amdgcn_mfma_f32_16x16x32_bf16(Efrag[mt][1], Bf[1][nt], z, 0, 0, 0);
        }

      // row scales: C/D rows = mt*16 + quad*4 + reg (broadcast reads, free)
      f32x4 fr[4];
#pragma unroll
      for (int mt = 0; mt < 4; ++mt) __builtin_memcpy(&fr[mt], f_lds + mt * 16 + quad * 4, 16);

#pragma unroll
      for (int mt = 0; mt < 4; ++mt)
#pragma unroll
        for (int nt = 0; nt < 4; ++nt) g[mt][nt] *= fr[mt];

      if (d == PD - 1) {  // renorm every 4 steps: growth <= ~2^14/step -> <= 2^56, safe
        f32x4 sv = {0.f, 0.f, 0.f, 0.f};
#pragma unroll
        for (int mt = 0; mt < 4; ++mt)
#pragma unroll
          for (int nt = 0; nt < 4; ++nt) sv += g[mt][nt];
        float r = (sv.x + sv.y) + (sv.z + sv.w);
#pragma unroll
        for (int off = 32; off >= 1; off >>= 1) r += __shfl_xor(r, off, 64);
        acc_log += __logf(r);
        const float inv = 1.0f / r;
#pragma unroll
        for (int mt = 0; mt < 4; ++mt)
#pragma unroll
          for (int nt = 0; nt < 4; ++nt) g[mt][nt] *= inv;
      }

      // pack + write back (in-order LDS keeps this after the Bf reads)
#pragma unroll
      for (int mt = 0; mt < 4; ++mt)
#pragma unroll
        for (int nt = 0; nt < 4; ++nt) {
          uint32 uu[2];
          uu[0] = pack_bf16_rnd(g[mt][nt].x, g[mt][nt].y);
          uu[1] = pack_bf16_rnd(g[mt][nt].z, g[mt][nt].w);
          __builtin_memcpy((char*)Mlds + ((mt >> 1) * 4 + nt) * 1024 +
                               ((mt & 1) * 2 + (quad >> 1)) * 256 + c0 * 16 + (quad & 1) * 8,
                           uu, 8);
        }
    }
  }
fin:
  __builtin_amdgcn_wave_barrier();
  // ---- dump M column-major: lane = column n; 8 contiguous-b128 LDS reads, coalesced stores ----
  {
    uint32* dst = wsM + (size_t)bc * 2048;
#pragma unroll
    for (int t = 0; t < 8; ++t) {  // k = 8t..8t+7 of column `lane`
      u32x4 v;
      __builtin_memcpy(&v, (const char*)Mlds + ((t >> 2) * 4 + (lane >> 4)) * 1024 +
                               (t & 3) * 256 + (lane & 15) * 16,
                       16);
      __builtin_memcpy(dst + t * 256 + lane * 4, &v, 16);
    }
    if (lane == 0) wsL[bc] = acc_log;
  }
}

// ---------------- kernel 2: backward stitch  v^T <- v^T * M_c  (lane = column) ----------------
__global__ __launch_bounds__(64) void crf_stitch_kernel(
    const uint32* __restrict__ wsM, const float* __restrict__ wsL,
    const float* __restrict__ trans, float* __restrict__ out) {
  const int b = blockIdx.x;
  const int lane = threadIdx.x;
  __shared__ __align__(16) float a_lds[TAG];

  u32x4 cur[8], nxt[8];
  {
    const uint32* p0 = wsM + ((size_t)b * K_CH + (K_CH - 1)) * 2048;
#pragma unroll
    for (int t = 0; t < 8; ++t) __builtin_memcpy(&cur[t], p0 + t * 256 + lane * 4, 16);
  }

  float a = __expf(trans[END_IDX * TAG + lane]);  // v0 = exp(trans[END,:]); lane 1 -> 0
  float tot = 0.0f;

  for (int c = K_CH - 1; c >= 0; --c) {
    if (c > 0) {
      const uint32* pn = wsM + ((size_t)b * K_CH + (c - 1)) * 2048;
#pragma unroll
      for (int t = 0; t < 8; ++t) __builtin_memcpy(&nxt[t], pn + t * 256 + lane * 4, 16);
    }
    a_lds[lane] = a;
    __builtin_amdgcn_wave_barrier();
    v2f acc[4] = {{0.f, 0.f}, {0.f, 0.f}, {0.f, 0.f}, {0.f, 0.f}};
#pragma unroll
    for (int t = 0; t < 8; ++t) {
#pragma unroll
      for (int e = 0; e < 4; ++e) {
        const uint32 u = cur[t][e];
        v2f m = {__uint_as_float(u << 16), __uint_as_float(u & 0xFFFF0000u)};
        v2f av;
        __builtin_memcpy(&av, a_lds + 8 * t + 2 * e, 8);  // broadcast read
        acc[e] += m * av;                                  // v_pk_fma_f32
      }
    }
    const v2f accT = (acc[0] + acc[1]) + (acc[2] + acc[3]);
    const float s = accT.x + accT.y;  // new v_lane (>=0)
    __builtin_amdgcn_wave_barrier();
    float r = s;
#pragma unroll
    for (int off = 32; off >= 1; off >>= 1) r += __shfl_xor(r, off, 64);
    tot += __logf(r);
    a = s / r;
    if (c > 0) {
#pragma unroll
      for (int t = 0; t < 8; ++t) cur[t] = nxt[t];
    }
  }

  float logs = tot;
#pragma unroll
  for (int c = 0; c < K_CH; ++c) logs += wsL[b * K_CH + c];
  // out = logs + log(v_final[START]); v_final[START] is lane START_IDX's a
  if (lane == START_IDX) out[b] = logs + __logf(a);
}

// ---------------- fallback (round-1 sequential kernel) if ws too small ----------------
__global__ __launch_bounds__(64) void crf_fwd_fallback(
    const float* __restrict__ feats, const float* __restrict__ mask,
    const float* __restrict__ trans, float* __restrict__ out) {
  const int b = blockIdx.x;
  const int lane = threadIdx.x;
  __shared__ float p_lds[TAG];
  v2f E[TAG / 2];
  {
    const float* row = trans + lane * TAG;
#pragma unroll
    for (int k = 0; k < TAG / 4; ++k) {
      f32x4 tv;
      __builtin_memcpy(&tv, row + 4 * k, 16);
      E[2 * k] = (v2f){__expf(tv.x), __expf(tv.y)};
      E[2 * k + 1] = (v2f){__expf(tv.z), __expf(tv.w)};
    }
  }
  float alpha = (lane == START_IDX) ? 0.0f : -10000.0f;
  float hatM = 0.0f;
  const float* fptr = feats + (size_t)b * TAG + lane;
  const float* mptr = mask + b;
  float fbuf[8], mbuf[8];
#pragma unroll
  for (int d = 0; d < 8; ++d) {
    fbuf[d] = fptr[(size_t)d * (BATCH * TAG)];
    mbuf[d] = mptr[(size_t)d * BATCH];
  }
  for (int sb = 0; sb < S_LEN; sb += 8) {
#pragma unroll
    for (int d = 0; d < 8; ++d) {
      const float fcur = fbuf[d], mcur = mbuf[d];
      if (mcur == 0.0f) goto fin;
      int sp = sb + d + 8;
      sp = (sp < S_LEN) ? sp : (S_LEN - 1);
      fbuf[d] = fptr[(size_t)sp * (BATCH * TAG)];
      mbuf[d] = mptr[(size_t)sp * BATCH];
      const float p = __expf(alpha - hatM);
      p_lds[lane] = p;
      __builtin_amdgcn_wave_barrier();
      v2f a0 = {0.f, 0.f}, a1 = {0.f, 0.f}, a2 = {0.f, 0.f}, a3 = {0.f, 0.f};
#pragma unroll
      for (int k = 0; k < TAG / 8; ++k) {
        v2f p0, p1, p2, p3;
        __builtin_memcpy(&p0, p_lds + 8 * k + 0, 8);
        __builtin_memcpy(&p1, p_lds + 8 * k + 2, 8);
        __builtin_memcpy(&p2, p_lds + 8 * k + 4, 8);
        __builtin_memcpy(&p3, p_lds + 8 * k + 6, 8);
        a0 += p0 * E[4 * k + 0];
        a1 += p1 * E[4 * k + 1];
        a2 += p2 * E[4 * k + 2];
        a3 += p3 * E[4 * k + 3];
      }
      const v2f aT = (a0 + a1) + (a2 + a3);
      alpha = fcur + hatM + __logf(aT.x + aT.y);
      hatM = __uint_as_float(__builtin_amdgcn_readlane(__float_as_uint(alpha), 2));
      __builtin_amdgcn_wave_barrier();
    }
  }
fin : {
  const float aend = alpha + trans[END_IDX * TAG + lane];
  float mx = aend;
#pragma unroll
  for (int off = 32; off >= 1; off >>= 1) mx = fmaxf(mx, __shfl_xor(mx, off, 64));
  float e = __expf(aend - mx);
#pragma unroll
  for (int off = 32; off >= 1; off >>= 1) e += __shfl_xor(e, off, 64);
  if (lane == 0) out[b] = mx + __logf(e);
}
}

extern "C" void kernel_launch(void* const* d_in, const int* in_sizes, int n_in,
                              void* d_out, int out_size, void* d_ws, size_t ws_size,
                              hipStream_t stream) {
  const float* feats = (const float*)d_in[0];
  const float* mask = (const float*)d_in[1];
  const float* trans = (const float*)d_in[2];
  float* out = (float*)d_out;

  const size_t wsM_bytes = (size_t)BATCH * K_CH * TAG * TAG * 2;  // 32 MiB
  const size_t need = wsM_bytes + (size_t)BATCH * K_CH * 4 + 256;
  if (ws_size < need) {
    crf_fwd_fallback<<<dim3(BATCH), dim3(64), 0, stream>>>(feats, mask, trans, out);
    return;
  }
  uint32* wsM = (uint32*)d_ws;
  float* wsL = (float*)((char*)d_ws + wsM_bytes);
  crf_chunk_kernel<<<dim3(BATCH * K_CH), dim3(64), 0, stream>>>(feats, mask, trans, wsM, wsL);
  crf_stitch_kernel<<<dim3(BATCH), dim3(64), 0, stream>>>(wsM, wsL, trans, out);
}

// Round 4
// 433.076 us; speedup vs baseline: 1.2540x; 1.2540x over previous
//
#include <hip/hip_runtime.h>

typedef short short8 __attribute__((ext_vector_type(8)));
typedef float f32x4 __attribute__((ext_vector_type(4)));
typedef float v2f __attribute__((ext_vector_type(2)));
typedef unsigned int uint32;
typedef uint32 u32x4 __attribute__((ext_vector_type(4)));

namespace {
constexpr int S_LEN = 512, BATCH = 1024, TAG = 64;
constexpr int START_IDX = 0, END_IDX = 1;
constexpr int PD = 4;  // prefetch depth == renorm cadence

// pack two fp32 -> two bf16, truncation (1 v_perm; round-2 showed same absmax as rounding)
__device__ __forceinline__ uint32 pack_bf16_trunc(float lo, float hi) {
  return __builtin_amdgcn_perm(__float_as_uint(hi), __float_as_uint(lo), 0x07060302u);
}
}  // namespace

// ---------------- kernel 1: per-(batch,chunk) transfer matrix via MFMA ----------------
// M <- diag(exp(feat_s)) * (E * M), E = exp(trans) const in A-frags.
// LDS layout (swizzled, 8 KiB): element (k,n) at byte
//   ((k>>5)*4 + (n>>4))*1024 + ((k>>3)&3)*256 + (n&15)*16 + (k&7)*2
// -> B-frag read (kb,nt): block kb*4+nt, byte lane*16 (lane-contiguous b128, conflict-free)
// -> D-write (mt,nt): 8B at ((mt>>1)*4+nt)*1024 + ((mt&1)*2+(quad>>1))*256 + c0*16 + (quad&1)*8
__global__ __launch_bounds__(64, 2) void crf_chunk_kernel(
    const float* __restrict__ feats, const float* __restrict__ mask,
    const float* __restrict__ trans, uint32* __restrict__ wsM,
    float* __restrict__ wsL, int K, int L, int kshift) {
  const int bc = blockIdx.x;
  const int b = bc >> kshift;
  const int c = bc & (K - 1);
  const int lane = threadIdx.x;
  const int c0 = lane & 15, quad = lane >> 4;

  __shared__ __align__(16) unsigned short Mlds[TAG * TAG];
  __shared__ __align__(16) float f_lds[TAG];

  // ---- init M = I ----
  {
    u32x4 z = {0u, 0u, 0u, 0u};
    u32x4* p = (u32x4*)Mlds;
#pragma unroll
    for (int t = 0; t < 8; ++t) p[lane + 64 * t] = z;
    __builtin_amdgcn_wave_barrier();
    char* idp = (char*)Mlds + ((lane >> 5) * 4 + (lane >> 4)) * 1024 +
                ((lane >> 3) & 3) * 256 + (lane & 15) * 16 + (lane & 7) * 2;
    *(unsigned short*)idp = 0x3F80;  // bf16 1.0 at (k=lane, n=lane)
    __builtin_amdgcn_wave_barrier();
  }

  // ---- E fragments (A-operand): A[m=c0+16mt][k=quad*8+j] per (mt,kb) ----
  short8 Efrag[4][2];
#pragma unroll
  for (int mt = 0; mt < 4; ++mt)
#pragma unroll
    for (int kb = 0; kb < 2; ++kb) {
      const float* src = trans + (mt * 16 + c0) * TAG + kb * 32 + quad * 8;
      f32x4 t0, t1;
      __builtin_memcpy(&t0, src, 16);
      __builtin_memcpy(&t1, src + 4, 16);
      uint32 uu[4];
      uu[0] = pack_bf16_trunc(__expf(t0.x), __expf(t0.y));  // exp(-1e4) -> 0, no NaN
      uu[1] = pack_bf16_trunc(__expf(t0.z), __expf(t0.w));
      uu[2] = pack_bf16_trunc(__expf(t1.x), __expf(t1.y));
      uu[3] = pack_bf16_trunc(__expf(t1.z), __expf(t1.w));
      __builtin_memcpy(&Efrag[mt][kb], uu, 16);
    }

  const size_t FSTRIDE = (size_t)BATCH * TAG;
  const float* fptr = feats + (size_t)(c * L) * FSTRIDE + (size_t)b * TAG + lane;
  const float* mptr = mask + (size_t)(c * L) * BATCH + b;

  float fbuf[PD], mbuf[PD];
#pragma unroll
  for (int d = 0; d < PD; ++d) {
    fbuf[d] = fptr[(size_t)d * FSTRIDE];
    mbuf[d] = mptr[(size_t)d * BATCH];
  }

  const f32x4 zero4 = {0.f, 0.f, 0.f, 0.f};  // persistent C=0 (no per-step acc zeroing)
  float acc_log = 0.0f;

  for (int sb = 0; sb < L; sb += PD) {
#pragma unroll
    for (int d = 0; d < PD; ++d) {
      const float fcur = fbuf[d];
      const float mcur = mbuf[d];
      // mask is lane-uniform & monotone: scalar test, s_cbranch (no exec churn)
      if (__builtin_amdgcn_readfirstlane(__float_as_uint(mcur)) == 0u) goto fin;
      int sp = sb + d + PD;
      sp = (sp < L) ? sp : (L - 1);
      fbuf[d] = fptr[(size_t)sp * FSTRIDE];
      mbuf[d] = mptr[(size_t)sp * BATCH];

      f_lds[lane] = __expf(fcur);  // row scales; ready by MFMA-end (in-order DS pipe)

      // B-frags: lane-contiguous b128 per (kb,nt)
      short8 Bf[2][4];
#pragma unroll
      for (int kb = 0; kb < 2; ++kb)
#pragma unroll
        for (int nt = 0; nt < 4; ++nt)
          __builtin_memcpy(&Bf[kb][nt], (const char*)Mlds + (kb * 4 + nt) * 1024 + lane * 16, 16);

      // phase 1: 16 independent MFMAs (K-low half), C = zero4
      f32x4 zt[4][4];
#pragma unroll
      for (int mt = 0; mt < 4; ++mt)
#pragma unroll
        for (int nt = 0; nt < 4; ++nt)
          zt[mt][nt] = __builtin_amdgcn_mfma_f32_16x16x32_bf16(Efrag[mt][0], Bf[0][nt], zero4, 0, 0, 0);
      // phase 2: 16 MFMAs (K-high half); each producer is >=16 issues old -> no stall
      f32x4 g[4][4];
#pragma unroll
      for (int mt = 0; mt < 4; ++mt)
#pragma unroll
        for (int nt = 0; nt < 4; ++nt)
          g[mt][nt] = __builtin_amdgcn_mfma_f32_16x16x32_bf16(Efrag[mt][1], Bf[1][nt], zt[mt][nt], 0, 0, 0);

      // row scales: C/D rows = mt*16 + quad*4 + reg (broadcast reads, conflict-free)
      f32x4 fr[4];
#pragma unroll
      for (int mt = 0; mt < 4; ++mt) __builtin_memcpy(&fr[mt], f_lds + mt * 16 + quad * 4, 16);
#pragma unroll
      for (int mt = 0; mt < 4; ++mt)
#pragma unroll
        for (int nt = 0; nt < 4; ++nt) g[mt][nt] *= fr[mt];

      if (d == PD - 1) {  // renorm every 4 steps (worst-case growth ~2^16/step -> safe)
        f32x4 sv = {0.f, 0.f, 0.f, 0.f};
#pragma unroll
        for (int mt = 0; mt < 4; ++mt)
#pragma unroll
          for (int nt = 0; nt < 4; ++nt) sv += g[mt][nt];
        float r = (sv.x + sv.y) + (sv.z + sv.w);
#pragma unroll
        for (int off = 32; off >= 1; off >>= 1) r += __shfl_xor(r, off, 64);
        acc_log += __logf(r);
        const float inv = 1.0f / r;
#pragma unroll
        for (int mt = 0; mt < 4; ++mt)
#pragma unroll
          for (int nt = 0; nt < 4; ++nt) g[mt][nt] *= inv;
      }

      // pack + write back (in-order DS pipe keeps this after the Bf reads)
#pragma unroll
      for (int mt = 0; mt < 4; ++mt)
#pragma unroll
        for (int nt = 0; nt < 4; ++nt) {
          uint32 uu[2];
          uu[0] = pack_bf16_trunc(g[mt][nt].x, g[mt][nt].y);
          uu[1] = pack_bf16_trunc(g[mt][nt].z, g[mt][nt].w);
          __builtin_memcpy((char*)Mlds + ((mt >> 1) * 4 + nt) * 1024 +
                               ((mt & 1) * 2 + (quad >> 1)) * 256 + c0 * 16 + (quad & 1) * 8,
                           uu, 8);
        }
    }
  }
fin:
  __builtin_amdgcn_wave_barrier();
  // ---- dump M column-major: lane = column n; contiguous b128 LDS reads, coalesced stores ----
  {
    uint32* dst = wsM + (size_t)bc * 2048;
#pragma unroll
    for (int t = 0; t < 8; ++t) {  // k = 8t..8t+7 of column `lane`
      u32x4 v;
      __builtin_memcpy(&v, (const char*)Mlds + ((t >> 2) * 4 + (lane >> 4)) * 1024 +
                               (t & 3) * 256 + (lane & 15) * 16,
                       16);
      __builtin_memcpy(dst + t * 256 + lane * 4, &v, 16);
    }
    if (lane == 0) wsL[bc] = acc_log;
  }
}

// ---------------- kernel 2: backward stitch  v^T <- v^T * M_c  (lane = column) ----------------
__global__ __launch_bounds__(64) void crf_stitch_kernel(
    const uint32* __restrict__ wsM, const float* __restrict__ wsL,
    const float* __restrict__ trans, float* __restrict__ out, int K) {
  const int b = blockIdx.x;
  const int lane = threadIdx.x;
  __shared__ __align__(16) float a_lds[TAG];

  u32x4 cur[8], nxt[8];
  {
    const uint32* p0 = wsM + ((size_t)b * K + (K - 1)) * 2048;
#pragma unroll
    for (int t = 0; t < 8; ++t) __builtin_memcpy(&cur[t], p0 + t * 256 + lane * 4, 16);
  }

  float a = __expf(trans[END_IDX * TAG + lane]);  // v0 = exp(trans[END,:])
  float tot = 0.0f;

  for (int c = K - 1; c >= 0; --c) {
    if (c > 0) {
      const uint32* pn = wsM + ((size_t)b * K + (c - 1)) * 2048;
#pragma unroll
      for (int t = 0; t < 8; ++t) __builtin_memcpy(&nxt[t], pn + t * 256 + lane * 4, 16);
    }
    a_lds[lane] = a;
    __builtin_amdgcn_wave_barrier();
    v2f acc[4] = {{0.f, 0.f}, {0.f, 0.f}, {0.f, 0.f}, {0.f, 0.f}};
#pragma unroll
    for (int t = 0; t < 8; ++t) {
#pragma unroll
      for (int e = 0; e < 4; ++e) {
        const uint32 u = cur[t][e];
        v2f m = {__uint_as_float(u << 16), __uint_as_float(u & 0xFFFF0000u)};
        v2f av;
        __builtin_memcpy(&av, a_lds + 8 * t + 2 * e, 8);  // broadcast read
        acc[e] += m * av;                                  // v_pk_fma_f32
      }
    }
    const v2f accT = (acc[0] + acc[1]) + (acc[2] + acc[3]);
    const float s = accT.x + accT.y;
    __builtin_amdgcn_wave_barrier();
    float r = s;
#pragma unroll
    for (int off = 32; off >= 1; off >>= 1) r += __shfl_xor(r, off, 64);
    tot += __logf(r);
    a = s / r;
    if (c > 0) {
#pragma unroll
      for (int t = 0; t < 8; ++t) cur[t] = nxt[t];
    }
  }

  float logs = tot;
  for (int c = 0; c < K; ++c) logs += wsL[b * K + c];
  if (lane == START_IDX) out[b] = logs + __logf(a);
}

// ---------------- fallback (round-1 sequential kernel) if ws too small ----------------
__global__ __launch_bounds__(64) void crf_fwd_fallback(
    const float* __restrict__ feats, const float* __restrict__ mask,
    const float* __restrict__ trans, float* __restrict__ out) {
  const int b = blockIdx.x;
  const int lane = threadIdx.x;
  __shared__ float p_lds[TAG];
  v2f E[TAG / 2];
  {
    const float* row = trans + lane * TAG;
#pragma unroll
    for (int k = 0; k < TAG / 4; ++k) {
      f32x4 tv;
      __builtin_memcpy(&tv, row + 4 * k, 16);
      E[2 * k] = (v2f){__expf(tv.x), __expf(tv.y)};
      E[2 * k + 1] = (v2f){__expf(tv.z), __expf(tv.w)};
    }
  }
  float alpha = (lane == START_IDX) ? 0.0f : -10000.0f;
  float hatM = 0.0f;
  const float* fptr = feats + (size_t)b * TAG + lane;
  const float* mptr = mask + b;
  float fbuf[8], mbuf[8];
#pragma unroll
  for (int d = 0; d < 8; ++d) {
    fbuf[d] = fptr[(size_t)d * (BATCH * TAG)];
    mbuf[d] = mptr[(size_t)d * BATCH];
  }
  for (int sb = 0; sb < S_LEN; sb += 8) {
#pragma unroll
    for (int d = 0; d < 8; ++d) {
      const float fcur = fbuf[d], mcur = mbuf[d];
      if (mcur == 0.0f) goto fin;
      int sp = sb + d + 8;
      sp = (sp < S_LEN) ? sp : (S_LEN - 1);
      fbuf[d] = fptr[(size_t)sp * (BATCH * TAG)];
      mbuf[d] = mptr[(size_t)sp * BATCH];
      const float p = __expf(alpha - hatM);
      p_lds[lane] = p;
      __builtin_amdgcn_wave_barrier();
      v2f a0 = {0.f, 0.f}, a1 = {0.f, 0.f}, a2 = {0.f, 0.f}, a3 = {0.f, 0.f};
#pragma unroll
      for (int k = 0; k < TAG / 8; ++k) {
        v2f p0, p1, p2, p3;
        __builtin_memcpy(&p0, p_lds + 8 * k + 0, 8);
        __builtin_memcpy(&p1, p_lds + 8 * k + 2, 8);
        __builtin_memcpy(&p2, p_lds + 8 * k + 4, 8);
        __builtin_memcpy(&p3, p_lds + 8 * k + 6, 8);
        a0 += p0 * E[4 * k + 0];
        a1 += p1 * E[4 * k + 1];
        a2 += p2 * E[4 * k + 2];
        a3 += p3 * E[4 * k + 3];
      }
      const v2f aT = (a0 + a1) + (a2 + a3);
      alpha = fcur + hatM + __logf(aT.x + aT.y);
      hatM = __uint_as_float(__builtin_amdgcn_readlane(__float_as_uint(alpha), 2));
      __builtin_amdgcn_wave_barrier();
    }
  }
fin : {
  const float aend = alpha + trans[END_IDX * TAG + lane];
  float mx = aend;
#pragma unroll
  for (int off = 32; off >= 1; off >>= 1) mx = fmaxf(mx, __shfl_xor(mx, off, 64));
  float e = __expf(aend - mx);
#pragma unroll
  for (int off = 32; off >= 1; off >>= 1) e += __shfl_xor(e, off, 64);
  if (lane == 0) out[b] = mx + __logf(e);
}
}

extern "C" void kernel_launch(void* const* d_in, const int* in_sizes, int n_in,
                              void* d_out, int out_size, void* d_ws, size_t ws_size,
                              hipStream_t stream) {
  const float* feats = (const float*)d_in[0];
  const float* mask = (const float*)d_in[1];
  const float* trans = (const float*)d_in[2];
  float* out = (float*)d_out;

  int K = 0, kshift = 0;
  {
    int ks = 3;
    for (int k = 8; k >= 2; k >>= 1, --ks) {
      size_t need = (size_t)BATCH * k * (TAG * TAG * 2 + 4) + 256;
      if (ws_size >= need) {
        K = k;
        kshift = ks;
        break;
      }
    }
  }
  if (K == 0) {
    crf_fwd_fallback<<<dim3(BATCH), dim3(64), 0, stream>>>(feats, mask, trans, out);
    return;
  }
  uint32* wsM = (uint32*)d_ws;
  float* wsL = (float*)((char*)d_ws + (size_t)BATCH * K * TAG * TAG * 2);
  crf_chunk_kernel<<<dim3(BATCH * K), dim3(64), 0, stream>>>(feats, mask, trans, wsM, wsL, K,
                                                             S_LEN / K, kshift);
  crf_stitch_kernel<<<dim3(BATCH), dim3(64), 0, stream>>>(wsM, wsL, trans, out, K);
}